// Round 9
// baseline (39.004 us; speedup 1.0000x reference)
//
#include <hip/hip_runtime.h>

#define NTYPES 100
#define EMBED 64
#define N_BATCH 9000
#define ATOMS_PER_MOL 64
#define N_ATOMS (N_BATCH * ATOMS_PER_MOL)   // 576000
#define N4 (N_ATOMS / 4)                    // 144000 int4
#define TOTAL4 (N_ATOMS * 16)               // 9,216,000 float4 outputs
#define MBLK 64                             // marker blocks (one slot each)
#define MTHR 256
#define GBLK 2048                           // 8 blocks/CU x 256 CUs
#define GTHR 256
#define GSTRIDE (GBLK * GTHR)               // 524288

typedef float    f32x4 __attribute__((ext_vector_type(4)));
typedef int      i32x4 __attribute__((ext_vector_type(4)));
typedef unsigned u32x4 __attribute__((ext_vector_type(4)));

// R8 post-mortem: gather invariant (38.6-39.0us) across NT/plain stores,
// 2/4-way unroll, 2/3 graph nodes. Last unfalsified overhead: per-block
// front-end (slot load -> LDS LUT -> 2x syncthreads before first store) and
// per-iter LDS rank reads. This version: ZERO LDS, ZERO syncthreads in the
// gather — per-wave register bitmap + pure-VALU rank (VALUBusy was 5%).

// ---------------------------------------------------------------------------
// Node 0: 64 blocks, each writes its PARTIAL presence bitmap (128 bits) to
// its own 16B slot. Plain unconditional store -> poison-safe, no atomics.
// Cross-dispatch visibility via kernel-boundary release (proven R2/R7/R8).
// ---------------------------------------------------------------------------
__global__ __launch_bounds__(MTHR) void ae_mark(const i32x4* __restrict__ at4,
                                                u32x4* __restrict__ slots) {
    const int tid = threadIdx.x;
    __shared__ unsigned s_bm[4];
    if (tid < 4) s_bm[tid] = 0u;
    __syncthreads();

    unsigned b0 = 0, b1 = 0, b2 = 0, b3 = 0;
    for (int i = blockIdx.x * MTHR + tid; i < N4; i += MBLK * MTHR) {  // ~8.8 iters
        i32x4 v = at4[i];
#define AE_SETBIT(t) { unsigned m = 1u << ((t) & 31); int j = (t) >> 5; \
        if (j == 0) b0 |= m; else if (j == 1) b1 |= m; \
        else if (j == 2) b2 |= m; else b3 |= m; }
        AE_SETBIT(v.x); AE_SETBIT(v.y); AE_SETBIT(v.z); AE_SETBIT(v.w);
#undef AE_SETBIT
    }
    for (int off = 32; off >= 1; off >>= 1) {   // 64-lane OR butterfly
        b0 |= __shfl_xor(b0, off);
        b1 |= __shfl_xor(b1, off);
        b2 |= __shfl_xor(b2, off);
        b3 |= __shfl_xor(b3, off);
    }
    if ((tid & 63) == 0) {                      // lane 0 of each of 4 waves
        atomicOr(&s_bm[0], b0);                 // LDS atomics (cheap)
        atomicOr(&s_bm[1], b1);
        atomicOr(&s_bm[2], b2);
        atomicOr(&s_bm[3], b3);
    }
    __syncthreads();
    if (tid == 0) {
        u32x4 w; w.x = s_bm[0]; w.y = s_bm[1]; w.z = s_bm[2]; w.w = s_bm[3];
        slots[blockIdx.x] = w;                  // plain 16B store, own slot
    }
}

// rank(t) = #present types strictly below t, from a 128-bit register bitmap.
__device__ __forceinline__ int ae_rank(int t, unsigned b0, unsigned b1,
                                       unsigned b2, unsigned b3,
                                       int c1, int c2, int c3) {
    int j = t >> 5;
    unsigned w = (j == 0) ? b0 : (j == 1) ? b1 : (j == 2) ? b2 : b3;
    int base   = (j == 0) ? 0  : (j == 1) ? c1 : (j == 2) ? c2 : c3;
    return base + __popc(w & ((1u << (t & 31)) - 1u));
}

// ---------------------------------------------------------------------------
// Node 1: gather — no LDS, no syncthreads. Per-wave: lane l loads slot l,
// 64-lane OR butterfly -> every lane holds the full bitmap in 4 VGPRs; rank
// resolved per-use in VALU. Main loop: 16 threads/atom, 4-way unrolled,
// plain coalesced 16B/lane stores.
// ---------------------------------------------------------------------------
__global__ __launch_bounds__(GTHR) void ae_gather(
        const int* __restrict__ atom_types,
        const f32x4* __restrict__ emb4,
        const u32x4* __restrict__ slots,
        f32x4* __restrict__ out4) {
    const int tid = threadIdx.x;

    u32x4 s = slots[tid & 63];                  // one slot per lane
    unsigned b0 = s.x, b1 = s.y, b2 = s.z, b3 = s.w;
    for (int off = 32; off >= 1; off >>= 1) {   // 64-lane OR butterfly
        b0 |= __shfl_xor(b0, off);
        b1 |= __shfl_xor(b1, off);
        b2 |= __shfl_xor(b2, off);
        b3 |= __shfl_xor(b3, off);
    }
    const int c1 = __popc(b0);
    const int c2 = c1 + __popc(b1);
    const int c3 = c2 + __popc(b2);

    const int gid = blockIdx.x * GTHR + tid;
    const int q = gid & 15;                     // float4 slot, invariant mod GSTRIDE
    int g = gid;
    for (; g + 3 * GSTRIDE < TOTAL4; g += 4 * GSTRIDE) {
        int t0 = atom_types[(g + 0 * GSTRIDE) >> 4];
        int t1 = atom_types[(g + 1 * GSTRIDE) >> 4];
        int t2 = atom_types[(g + 2 * GSTRIDE) >> 4];
        int t3 = atom_types[(g + 3 * GSTRIDE) >> 4];
        int r0 = ae_rank(t0, b0, b1, b2, b3, c1, c2, c3);
        int r1 = ae_rank(t1, b0, b1, b2, b3, c1, c2, c3);
        int r2 = ae_rank(t2, b0, b1, b2, b3, c1, c2, c3);
        int r3 = ae_rank(t3, b0, b1, b2, b3, c1, c2, c3);
        f32x4 v0 = emb4[r0 * 16 + q];           // 25.6KB table, L1-resident
        f32x4 v1 = emb4[r1 * 16 + q];
        f32x4 v2 = emb4[r2 * 16 + q];
        f32x4 v3 = emb4[r3 * 16 + q];
        out4[g + 0 * GSTRIDE] = v0;
        out4[g + 1 * GSTRIDE] = v1;
        out4[g + 2 * GSTRIDE] = v2;
        out4[g + 3 * GSTRIDE] = v3;
    }
    for (; g < TOTAL4; g += GSTRIDE) {
        int t = atom_types[g >> 4];
        int r = ae_rank(t, b0, b1, b2, b3, c1, c2, c3);
        out4[g] = emb4[r * 16 + q];
    }
}

extern "C" void kernel_launch(void* const* d_in, const int* in_sizes, int n_in,
                              void* d_out, int out_size, void* d_ws, size_t ws_size,
                              hipStream_t stream) {
    const int* atom_types  = (const int*)d_in[0];    // [9000,64] int32
    const float* embedding = (const float*)d_in[1];  // [100,64]  f32
    float* out             = (float*)d_out;          // [9000,64,64] f32

    u32x4* slots = (u32x4*)d_ws;   // 64 x 16B partial bitmaps (fully rewritten each call)

    ae_mark<<<MBLK, MTHR, 0, stream>>>((const i32x4*)atom_types, slots);
    ae_gather<<<GBLK, GTHR, 0, stream>>>(atom_types, (const f32x4*)embedding,
                                         slots, (f32x4*)out);
}

// Round 10
// 38.802 us; speedup vs baseline: 1.0052x; 1.0052x over previous
//
#include <hip/hip_runtime.h>

#define NTYPES 100
#define EMBED 64
#define N_BATCH 9000
#define ATOMS_PER_MOL 64
#define N_ATOMS (N_BATCH * ATOMS_PER_MOL)   // 576000
#define N4 (N_ATOMS / 4)                    // 144000 int4
#define TOTAL4 (N_ATOMS * 16)               // 9,216,000 float4 outputs
#define MBLK 64                             // marker blocks (one slot each)
#define MTHR 256
#define GBLK 2000                           // 2000*256 threads -> exactly 18 iters
#define GTHR 256
#define GSTRIDE (GBLK * GTHR)               // 512000 (f32x4 units per iter step)
#define GITERS 18                           // TOTAL4 / GSTRIDE, exact, no tail

typedef float    f32x4 __attribute__((ext_vector_type(4)));
typedef int      i32x4 __attribute__((ext_vector_type(4)));
typedef unsigned u32x4 __attribute__((ext_vector_type(4)));

// R9 post-mortem: gather pinned at ~4.5 TB/s across every structural knob,
// while 8-VGPR fills hit 6.5 TB/s at 10% occupancy. Theory: vmcnt is a FIFO
// shared by loads+stores; our loop's dependent-load waits drain past earlier
// stores, coupling the wave to store-ack latency. Fix: ALL loads issued
// before ALL stores (load->rank->load-all-emb->store-all), so waitcnt
// brackets let stores stay outstanding and the store stream runs fill-like.

// ---------------------------------------------------------------------------
// Node 0: 64 blocks, each writes its PARTIAL presence bitmap (128 bits) to
// its own 16B slot. Plain unconditional store -> poison-safe, no atomics.
// Cross-dispatch visibility via kernel-boundary release (proven R2/R7-R9).
// ---------------------------------------------------------------------------
__global__ __launch_bounds__(MTHR) void ae_mark(const i32x4* __restrict__ at4,
                                                u32x4* __restrict__ slots) {
    const int tid = threadIdx.x;
    __shared__ unsigned s_bm[4];
    if (tid < 4) s_bm[tid] = 0u;
    __syncthreads();

    unsigned b0 = 0, b1 = 0, b2 = 0, b3 = 0;
    for (int i = blockIdx.x * MTHR + tid; i < N4; i += MBLK * MTHR) {  // ~8.8 iters
        i32x4 v = at4[i];
#define AE_SETBIT(t) { unsigned m = 1u << ((t) & 31); int j = (t) >> 5; \
        if (j == 0) b0 |= m; else if (j == 1) b1 |= m; \
        else if (j == 2) b2 |= m; else b3 |= m; }
        AE_SETBIT(v.x); AE_SETBIT(v.y); AE_SETBIT(v.z); AE_SETBIT(v.w);
#undef AE_SETBIT
    }
    for (int off = 32; off >= 1; off >>= 1) {   // 64-lane OR butterfly
        b0 |= __shfl_xor(b0, off);
        b1 |= __shfl_xor(b1, off);
        b2 |= __shfl_xor(b2, off);
        b3 |= __shfl_xor(b3, off);
    }
    if ((tid & 63) == 0) {                      // lane 0 of each of 4 waves
        atomicOr(&s_bm[0], b0);                 // LDS atomics (cheap)
        atomicOr(&s_bm[1], b1);
        atomicOr(&s_bm[2], b2);
        atomicOr(&s_bm[3], b3);
    }
    __syncthreads();
    if (tid == 0) {
        u32x4 w; w.x = s_bm[0]; w.y = s_bm[1]; w.z = s_bm[2]; w.w = s_bm[3];
        slots[blockIdx.x] = w;                  // plain 16B store, own slot
    }
}

// rank(t) = #present types strictly below t, from a 128-bit register bitmap.
__device__ __forceinline__ int ae_rank(int t, unsigned b0, unsigned b1,
                                       unsigned b2, unsigned b3,
                                       int c1, int c2, int c3) {
    int j = t >> 5;
    unsigned w = (j == 0) ? b0 : (j == 1) ? b1 : (j == 2) ? b2 : b3;
    int base   = (j == 0) ? 0  : (j == 1) ? c1 : (j == 2) ? c2 : c3;
    return base + __popc(w & ((1u << (t & 31)) - 1u));
}

// ---------------------------------------------------------------------------
// Node 1: gather, fully hoisted. No LDS, no syncthreads. Per wave: lane l
// loads slot l, OR-butterfly -> full bitmap in 4 VGPRs. Then: 18 t-loads ->
// 18 VALU ranks -> 18 emb f32x4 loads -> 18 stores. All loads precede all
// stores in the vmcnt FIFO, so store acks never gate load consumption.
// All loops are constant-trip and fully unrolled -> arrays stay in registers.
// ---------------------------------------------------------------------------
__global__ __launch_bounds__(GTHR) void ae_gather(
        const int* __restrict__ atom_types,
        const f32x4* __restrict__ emb4,
        const u32x4* __restrict__ slots,
        f32x4* __restrict__ out4) {
    const int tid = threadIdx.x;

    u32x4 s = slots[tid & 63];                  // one slot per lane
    unsigned b0 = s.x, b1 = s.y, b2 = s.z, b3 = s.w;
    for (int off = 32; off >= 1; off >>= 1) {   // 64-lane OR butterfly
        b0 |= __shfl_xor(b0, off);
        b1 |= __shfl_xor(b1, off);
        b2 |= __shfl_xor(b2, off);
        b3 |= __shfl_xor(b3, off);
    }
    const int c1 = __popc(b0);
    const int c2 = c1 + __popc(b1);
    const int c3 = c2 + __popc(b2);

    const int gid   = blockIdx.x * GTHR + tid;  // < 512000
    const int q     = gid & 15;                 // float4 slot (stride keeps it fixed)
    const int atom0 = gid >> 4;                 // atoms advance by 32000/iter

    // Phase 1: all atom-type loads (independent, issue back-to-back).
    int r[GITERS];
#pragma unroll
    for (int i = 0; i < GITERS; ++i)
        r[i] = atom_types[atom0 + i * (GSTRIDE >> 4)];

    // Phase 2: ranks in VALU (waits only on the t-loads).
#pragma unroll
    for (int i = 0; i < GITERS; ++i)
        r[i] = ae_rank(r[i], b0, b1, b2, b3, c1, c2, c3);

    // Phase 3: all embedding-row loads (L1/L2-resident 25.6 KB table).
    f32x4 v[GITERS];
#pragma unroll
    for (int i = 0; i < GITERS; ++i)
        v[i] = emb4[r[i] * 16 + q];

    // Phase 4: all stores. waitcnt brackets (vmcnt(17)...) drain only the
    // loads; stores pile up outstanding like a fill kernel.
#pragma unroll
    for (int i = 0; i < GITERS; ++i)
        out4[gid + i * GSTRIDE] = v[i];
}

extern "C" void kernel_launch(void* const* d_in, const int* in_sizes, int n_in,
                              void* d_out, int out_size, void* d_ws, size_t ws_size,
                              hipStream_t stream) {
    const int* atom_types  = (const int*)d_in[0];    // [9000,64] int32
    const float* embedding = (const float*)d_in[1];  // [100,64]  f32
    float* out             = (float*)d_out;          // [9000,64,64] f32

    u32x4* slots = (u32x4*)d_ws;   // 64 x 16B partial bitmaps (fully rewritten each call)

    ae_mark<<<MBLK, MTHR, 0, stream>>>((const i32x4*)atom_types, slots);
    ae_gather<<<GBLK, GTHR, 0, stream>>>(atom_types, (const f32x4*)embedding,
                                         slots, (f32x4*)out);
}